// Round 3
// baseline (713.572 us; speedup 1.0000x reference)
//
#include <hip/hip_runtime.h>
#include <hip/hip_bf16.h>

#define N 8192
#define H 256

typedef __attribute__((ext_vector_type(8))) short bf16x8;   // 8 bf16 (4 VGPRs)
typedef __attribute__((ext_vector_type(4))) float f32x4;
typedef __attribute__((ext_vector_type(4))) _Float16 h4;

// ---------------------------------------------------------------------------
// Kernel 0: W (fp32, 256x256) -> bf16
__global__ __launch_bounds__(256) void convw_kernel(
    const float* __restrict__ W, __hip_bfloat16* __restrict__ Wb)
{
    int i = (blockIdx.x * 256 + threadIdx.x) * 4;   // 64 blocks cover 65536
    float4 w = *(const float4*)(W + i);
    __hip_bfloat16 o[4] = {__float2bfloat16(w.x), __float2bfloat16(w.y),
                           __float2bfloat16(w.z), __float2bfloat16(w.w)};
    *(short4*)(Wb + i) = *(short4*)o;
}

// ---------------------------------------------------------------------------
// Kernel 1 (MFMA): z = elu(x @ W^T + b); zh = bf16(z/||z||).
// v2: block = 16 rows x 256 cols, 4 waves each owning 64 cols (4 nt-tiles).
// Grid (512,2) -> 16 waves/CU (was 4). Row-norm cross-wave via tiny LDS.
__global__ __launch_bounds__(256) void proj_kernel(
    const float* __restrict__ v1, const float* __restrict__ v2,
    const __hip_bfloat16* __restrict__ Wb, const float* __restrict__ bias,
    __hip_bfloat16* __restrict__ zh1, __hip_bfloat16* __restrict__ zh2)
{
    __shared__ float partial[4][16];
    const float* x = blockIdx.y ? v2 : v1;
    __hip_bfloat16* zh = blockIdx.y ? zh2 : zh1;
    int lane = threadIdx.x & 63, wc = threadIdx.x >> 6;
    int r16 = lane & 15, quad = lane >> 4;

    long row0 = (long)blockIdx.x * 16;
    const float* xr = x + (row0 + r16) * H + quad * 8;
    // wave wc covers output cols [wc*64, wc*64+64): nt tiles j=0..3
    const __hip_bfloat16* wb = Wb + (wc * 64 + r16) * H + quad * 8;

    f32x4 acc[4] = {};
#pragma unroll
    for (int k8 = 0; k8 < 8; ++k8) {
        float4 xa = *(const float4*)(xr + k8 * 32);
        float4 xb = *(const float4*)(xr + k8 * 32 + 4);
        union { bf16x8 v; __hip_bfloat16 h[8]; } u;
        u.h[0] = __float2bfloat16(xa.x); u.h[1] = __float2bfloat16(xa.y);
        u.h[2] = __float2bfloat16(xa.z); u.h[3] = __float2bfloat16(xa.w);
        u.h[4] = __float2bfloat16(xb.x); u.h[5] = __float2bfloat16(xb.y);
        u.h[6] = __float2bfloat16(xb.z); u.h[7] = __float2bfloat16(xb.w);
#pragma unroll
        for (int j = 0; j < 4; ++j) {
            bf16x8 bf = *(const bf16x8*)(wb + j * 16 * H + k8 * 32);
            acc[j] = __builtin_amdgcn_mfma_f32_16x16x32_bf16(u.v, bf, acc[j], 0, 0, 0);
        }
    }

    // Epilogue. C/D: col = wc*64 + j*16 + r16, row = quad*4 + g.
    float ss[4] = {};
#pragma unroll
    for (int j = 0; j < 4; ++j) {
        float bc = bias[wc * 64 + j * 16 + r16];
#pragma unroll
        for (int g = 0; g < 4; ++g) {
            float v = acc[j][g] + bc;
            v = v > 0.f ? v : (__expf(v) - 1.f);   // ELU alpha=1
            acc[j][g] = v;
            ss[g] = fmaf(v, v, ss[g]);
        }
    }
    // reduce ss over the 16 r16-lanes of each quad -> per-wave 64-col partial
#pragma unroll
    for (int g = 0; g < 4; ++g) {
#pragma unroll
        for (int o = 1; o < 16; o <<= 1) ss[g] += __shfl_xor(ss[g], o);
    }
    if (r16 == 0) {
#pragma unroll
        for (int g = 0; g < 4; ++g) partial[wc][quad * 4 + g] = ss[g];
    }
    __syncthreads();
#pragma unroll
    for (int g = 0; g < 4; ++g) {
        int row = quad * 4 + g;
        float tot = partial[0][row] + partial[1][row] + partial[2][row] + partial[3][row];
        float inv = rsqrtf(tot);
#pragma unroll
        for (int j = 0; j < 4; ++j)
            zh[(row0 + row) * H + wc * 64 + j * 16 + r16] =
                __float2bfloat16(acc[j][g] * inv);
    }
}

// ---------------------------------------------------------------------------
// Kernel 2a: e = exp(2*cos(z1,z2)) -> fp16 global, fully coalesced via LDS.
// Structure = round-0 verified contrast MFMA+exp+LDS phases; streaming removed.
__global__ __launch_bounds__(256) void ecomp_kernel(
    const __hip_bfloat16* __restrict__ zh1, const __hip_bfloat16* __restrict__ zh2,
    _Float16* __restrict__ e)
{
    __shared__ _Float16 elds[128][132];
    int lane = threadIdx.x & 63;
    int wave = threadIdx.x >> 6;
    int wr = wave >> 1, wc = wave & 1;
    int r16 = lane & 15, quad = lane >> 4;
    long row0 = (long)blockIdx.x * 128 + wr * 64;
    long col0 = (long)blockIdx.y * 128 + wc * 64;

    f32x4 acc[4][4] = {};
    const __hip_bfloat16* ap = zh1 + (row0 + r16) * H + quad * 8;
    const __hip_bfloat16* bp = zh2 + (col0 + r16) * H + quad * 8;
#pragma unroll
    for (int k = 0; k < H; k += 32) {
        bf16x8 a[4], b[4];
#pragma unroll
        for (int t = 0; t < 4; ++t) a[t] = *(const bf16x8*)(ap + t * 16 * H + k);
#pragma unroll
        for (int t = 0; t < 4; ++t) b[t] = *(const bf16x8*)(bp + t * 16 * H + k);
#pragma unroll
        for (int mi = 0; mi < 4; ++mi)
#pragma unroll
            for (int nj = 0; nj < 4; ++nj)
                acc[mi][nj] = __builtin_amdgcn_mfma_f32_16x16x32_bf16(
                    a[mi], b[nj], acc[mi][nj], 0, 0, 0);
    }

    // exp(2*cos) -> LDS. C/D: col=lane&15, row=quad*4+reg.
#pragma unroll
    for (int mi = 0; mi < 4; ++mi) {
        int lrow = wr * 64 + mi * 16 + quad * 4;
#pragma unroll
        for (int nj = 0; nj < 4; ++nj) {
            int lcol = wc * 64 + nj * 16 + r16;
#pragma unroll
            for (int g = 0; g < 4; ++g)
                elds[lrow + g][lcol] = (_Float16)__expf(acc[mi][nj][g] * 2.0f);
        }
    }
    __syncthreads();

    // coalesced store: per iter 16 rows x (32 lanes x h4 = 128B contiguous)... 
    // idx>>5 = 8 rows/iter, 16 iters cover 128 rows.
    _Float16* eb = e + ((long)blockIdx.x * 128) * N + (long)blockIdx.y * 128;
#pragma unroll
    for (int it = 0; it < 16; ++it) {
        int idx = threadIdx.x + it * 256;
        long r = idx >> 5;
        int c = (idx & 31) * 4;
        *(h4*)(eb + r * N + c) = *(const h4*)&elds[r][c];
    }
}

// ---------------------------------------------------------------------------
// Kernel 2b: pure streamer. sp += e*pos, sn += e*neg over all 67.1M elems.
// Grid-stride, zero LDS / zero sync in loop, 8 blocks/CU, full occupancy.
__global__ __launch_bounds__(256) void reduce_kernel(
    const _Float16* __restrict__ e, const float* __restrict__ pos,
    const float* __restrict__ neg, float* __restrict__ bins)
{
    size_t t = (size_t)blockIdx.x * 256 + threadIdx.x;   // 524288 threads
    float sp = 0.f, sn = 0.f;
    for (int k = 0; k < 32; k += 4) {
        h4 ev[4]; float4 pv[4], nv[4];
#pragma unroll
        for (int j = 0; j < 4; ++j) {
            size_t base = (t + (size_t)(k + j) * 524288) * 4;
            ev[j] = *(const h4*)(e + base);
            pv[j] = *(const float4*)(pos + base);
            nv[j] = *(const float4*)(neg + base);
        }
#pragma unroll
        for (int j = 0; j < 4; ++j) {
            sp = fmaf((float)ev[j].x, pv[j].x, sp);
            sp = fmaf((float)ev[j].y, pv[j].y, sp);
            sp = fmaf((float)ev[j].z, pv[j].z, sp);
            sp = fmaf((float)ev[j].w, pv[j].w, sp);
            sn = fmaf((float)ev[j].x, nv[j].x, sn);
            sn = fmaf((float)ev[j].y, nv[j].y, sn);
            sn = fmaf((float)ev[j].z, nv[j].z, sn);
            sn = fmaf((float)ev[j].w, nv[j].w, sn);
        }
    }
#pragma unroll
    for (int o = 32; o > 0; o >>= 1) {
        sp += __shfl_down(sp, o);
        sn += __shfl_down(sn, o);
    }
    __shared__ float wsum[4][2];
    int lane = threadIdx.x & 63, wave = threadIdx.x >> 6;
    if (lane == 0) { wsum[wave][0] = sp; wsum[wave][1] = sn; }
    __syncthreads();
    if (threadIdx.x == 0) {
        float bsp = wsum[0][0] + wsum[1][0] + wsum[2][0] + wsum[3][0];
        float bsn = wsum[0][1] + wsum[1][1] + wsum[2][1] + wsum[3][1];
        int bin = blockIdx.x & 63;
        atomicAdd(&bins[bin], bsp);
        atomicAdd(&bins[64 + bin], bsn);
    }
}

// ---------------------------------------------------------------------------
// Fallback fused contrast (round-0 harness-verified, 242 us) for small ws.
__global__ __launch_bounds__(256) void contrast_kernel(
    const __hip_bfloat16* __restrict__ zh1, const __hip_bfloat16* __restrict__ zh2,
    const float* __restrict__ pos, const float* __restrict__ neg,
    float* __restrict__ bins)
{
    __shared__ _Float16 elds[128][132];
    int lane = threadIdx.x & 63;
    int wave = threadIdx.x >> 6;
    int wr = wave >> 1, wc = wave & 1;
    int r16 = lane & 15, quad = lane >> 4;
    long row0 = (long)blockIdx.x * 128 + wr * 64;
    long col0 = (long)blockIdx.y * 128 + wc * 64;

    f32x4 acc[4][4] = {};
    const __hip_bfloat16* ap = zh1 + (row0 + r16) * H + quad * 8;
    const __hip_bfloat16* bp = zh2 + (col0 + r16) * H + quad * 8;
#pragma unroll
    for (int k = 0; k < H; k += 32) {
        bf16x8 a[4], b[4];
#pragma unroll
        for (int t = 0; t < 4; ++t) a[t] = *(const bf16x8*)(ap + t * 16 * H + k);
#pragma unroll
        for (int t = 0; t < 4; ++t) b[t] = *(const bf16x8*)(bp + t * 16 * H + k);
#pragma unroll
        for (int mi = 0; mi < 4; ++mi)
#pragma unroll
            for (int nj = 0; nj < 4; ++nj)
                acc[mi][nj] = __builtin_amdgcn_mfma_f32_16x16x32_bf16(
                    a[mi], b[nj], acc[mi][nj], 0, 0, 0);
    }
#pragma unroll
    for (int mi = 0; mi < 4; ++mi) {
        int lrow = wr * 64 + mi * 16 + quad * 4;
#pragma unroll
        for (int nj = 0; nj < 4; ++nj) {
            int lcol = wc * 64 + nj * 16 + r16;
#pragma unroll
            for (int g = 0; g < 4; ++g)
                elds[lrow + g][lcol] = (_Float16)__expf(acc[mi][nj][g] * 2.0f);
        }
    }
    __syncthreads();

    const float* pb = pos + ((long)blockIdx.x * 128) * N + (long)blockIdx.y * 128;
    const float* nb = neg + ((long)blockIdx.x * 128) * N + (long)blockIdx.y * 128;
    float sp = 0.f, sn = 0.f;
#pragma unroll
    for (int half = 0; half < 2; ++half) {
        float4 pv[8], nv[8];
#pragma unroll
        for (int it = 0; it < 8; ++it) {
            int idx = threadIdx.x + (half * 8 + it) * 256;
            long r = idx >> 5;
            int c = (idx & 31) * 4;
            pv[it] = *(const float4*)(pb + r * N + c);
            nv[it] = *(const float4*)(nb + r * N + c);
        }
#pragma unroll
        for (int it = 0; it < 8; ++it) {
            int idx = threadIdx.x + (half * 8 + it) * 256;
            int r = idx >> 5;
            int c = (idx & 31) * 4;
            h4 ev = *(const h4*)&elds[r][c];
            sp = fmaf((float)ev.x, pv[it].x, sp);
            sp = fmaf((float)ev.y, pv[it].y, sp);
            sp = fmaf((float)ev.z, pv[it].z, sp);
            sp = fmaf((float)ev.w, pv[it].w, sp);
            sn = fmaf((float)ev.x, nv[it].x, sn);
            sn = fmaf((float)ev.y, nv[it].y, sn);
            sn = fmaf((float)ev.z, nv[it].z, sn);
            sn = fmaf((float)ev.w, nv[it].w, sn);
        }
    }
#pragma unroll
    for (int o = 32; o > 0; o >>= 1) {
        sp += __shfl_down(sp, o);
        sn += __shfl_down(sn, o);
    }
    __shared__ float wsum[4][2];
    if (lane == 0) { wsum[wave][0] = sp; wsum[wave][1] = sn; }
    __syncthreads();
    if (threadIdx.x == 0) {
        float bsp = wsum[0][0] + wsum[1][0] + wsum[2][0] + wsum[3][0];
        float bsn = wsum[0][1] + wsum[1][1] + wsum[2][1] + wsum[3][1];
        int bin = blockIdx.x & 63;
        atomicAdd(&bins[bin], bsp);
        atomicAdd(&bins[64 + bin], bsn);
    }
}

// ---------------------------------------------------------------------------
__global__ void final_kernel(const float* __restrict__ bins, float* __restrict__ out)
{
    int lane = threadIdx.x;  // 64 threads = 1 wave
    float sp = bins[lane], sn = bins[64 + lane];
#pragma unroll
    for (int o = 32; o > 0; o >>= 1) {
        sp += __shfl_down(sp, o);
        sn += __shfl_down(sn, o);
    }
    if (lane == 0) out[0] = -logf(sp / (sp + sn));
}

// ---------------------------------------------------------------------------
extern "C" void kernel_launch(void* const* d_in, const int* in_sizes, int n_in,
                              void* d_out, int out_size, void* d_ws, size_t ws_size,
                              hipStream_t stream)
{
    const float* v1   = (const float*)d_in[0];
    const float* v2   = (const float*)d_in[1];
    const float* pos  = (const float*)d_in[2];
    const float* neg  = (const float*)d_in[3];
    const float* W    = (const float*)d_in[4];
    const float* bias = (const float*)d_in[5];

    const size_t ebytes = (size_t)N * N * sizeof(_Float16);        // 134 MB
    const size_t zbytes = (size_t)N * H * sizeof(__hip_bfloat16);  // 4 MB
    const size_t need_big = ebytes + 2 * zbytes + (size_t)H * H * 2 + 512;
    bool big = ws_size >= need_big;

    char* p = (char*)d_ws;
    _Float16* e = nullptr;
    if (big) { e = (_Float16*)p; p += ebytes; }
    __hip_bfloat16* zh1 = (__hip_bfloat16*)p;           p += zbytes;
    __hip_bfloat16* zh2 = (__hip_bfloat16*)p;           p += zbytes;
    __hip_bfloat16* Wb  = (__hip_bfloat16*)p;           p += (size_t)H * H * 2;
    float* bins = (float*)p;

    hipMemsetAsync(bins, 0, 128 * sizeof(float), stream);
    convw_kernel<<<64, 256, 0, stream>>>(W, Wb);
    proj_kernel<<<dim3(N / 16, 2), 256, 0, stream>>>(v1, v2, Wb, bias, zh1, zh2);
    if (big) {
        ecomp_kernel<<<dim3(N / 128, N / 128), 256, 0, stream>>>(zh1, zh2, e);
        reduce_kernel<<<2048, 256, 0, stream>>>(e, pos, neg, bins);
    } else {
        contrast_kernel<<<dim3(N / 128, N / 128), 256, 0, stream>>>(zh1, zh2, pos, neg, bins);
    }
    final_kernel<<<1, 64, 0, stream>>>(bins, (float*)d_out);
}

// Round 4
// 651.552 us; speedup vs baseline: 1.0952x; 1.0952x over previous
//
#include <hip/hip_runtime.h>
#include <hip/hip_bf16.h>

#define N 8192
#define H 256

typedef __attribute__((ext_vector_type(8))) short bf16x8;   // 8 bf16 (4 VGPRs)
typedef __attribute__((ext_vector_type(4))) float f32x4;
typedef __attribute__((ext_vector_type(4))) _Float16 h4;

// ---------------------------------------------------------------------------
// Kernel 0: W (fp32, 256x256) -> bf16
__global__ __launch_bounds__(256) void convw_kernel(
    const float* __restrict__ W, __hip_bfloat16* __restrict__ Wb)
{
    int i = (blockIdx.x * 256 + threadIdx.x) * 4;   // 64 blocks cover 65536
    float4 w = *(const float4*)(W + i);
    __hip_bfloat16 o[4] = {__float2bfloat16(w.x), __float2bfloat16(w.y),
                           __float2bfloat16(w.z), __float2bfloat16(w.w)};
    *(short4*)(Wb + i) = *(short4*)o;
}

// ---------------------------------------------------------------------------
// Kernel 1 (MFMA): z = elu(x @ W^T + b); zh = bf16(z/||z||).
// Round-0 harness-verified version, unchanged.
__global__ __launch_bounds__(256) void proj_kernel(
    const float* __restrict__ v1, const float* __restrict__ v2,
    const __hip_bfloat16* __restrict__ Wb, const float* __restrict__ bias,
    __hip_bfloat16* __restrict__ zh1, __hip_bfloat16* __restrict__ zh2)
{
    const float* x = blockIdx.y ? v2 : v1;
    __hip_bfloat16* zh = blockIdx.y ? zh2 : zh1;
    int lane = threadIdx.x & 63, wave = threadIdx.x >> 6;
    int r16 = lane & 15, quad = lane >> 4;

    long arow = (long)blockIdx.x * 64 + wave * 16 + r16;
    const float* xr = x + arow * H + quad * 8;
    const __hip_bfloat16* wb = Wb + r16 * H + quad * 8;

    f32x4 acc[16] = {};
#pragma unroll
    for (int k8 = 0; k8 < 8; ++k8) {
        float4 xa = *(const float4*)(xr + k8 * 32);
        float4 xb = *(const float4*)(xr + k8 * 32 + 4);
        union { bf16x8 v; __hip_bfloat16 h[8]; } u;
        u.h[0] = __float2bfloat16(xa.x); u.h[1] = __float2bfloat16(xa.y);
        u.h[2] = __float2bfloat16(xa.z); u.h[3] = __float2bfloat16(xa.w);
        u.h[4] = __float2bfloat16(xb.x); u.h[5] = __float2bfloat16(xb.y);
        u.h[6] = __float2bfloat16(xb.z); u.h[7] = __float2bfloat16(xb.w);
#pragma unroll
        for (int nt = 0; nt < 16; ++nt) {
            bf16x8 bf = *(const bf16x8*)(wb + nt * 16 * H + k8 * 32);
            acc[nt] = __builtin_amdgcn_mfma_f32_16x16x32_bf16(u.v, bf, acc[nt], 0, 0, 0);
        }
    }

    float ss[4] = {};
#pragma unroll
    for (int nt = 0; nt < 16; ++nt) {
        float bc = bias[nt * 16 + r16];
#pragma unroll
        for (int g = 0; g < 4; ++g) {
            float v = acc[nt][g] + bc;
            v = v > 0.f ? v : (__expf(v) - 1.f);   // ELU alpha=1
            acc[nt][g] = v;
            ss[g] = fmaf(v, v, ss[g]);
        }
    }
    long crow0 = (long)blockIdx.x * 64 + wave * 16 + quad * 4;
#pragma unroll
    for (int g = 0; g < 4; ++g) {
        float s = ss[g];
#pragma unroll
        for (int o = 1; o < 16; o <<= 1) s += __shfl_xor(s, o);
        float inv = rsqrtf(s);
#pragma unroll
        for (int nt = 0; nt < 16; ++nt)
            zh[(crow0 + g) * H + nt * 16 + r16] = __float2bfloat16(acc[nt][g] * inv);
    }
}

// ---------------------------------------------------------------------------
// Kernel 2: fused contrast, barrier-free. Block = 128 rows x 64 cols, 4 waves;
// wave w owns rows [w*32, w*32+32) x all 64 cols: MFMA (2x4 tiles) -> exp ->
// wave-private LDS slab -> issue all 16 pos/neg float4 loads -> consume.
// Wave streams exactly the rows it computed => no __syncthreads anywhere.
// Phase order keeps loads adjacent to consume (anti-sink, per round-3 reduce).
__global__ __launch_bounds__(256) void contrast_kernel(
    const __hip_bfloat16* __restrict__ zh1, const __hip_bfloat16* __restrict__ zh2,
    const float* __restrict__ pos, const float* __restrict__ neg,
    float* __restrict__ bins)
{
    __shared__ _Float16 elds[4][32][68];   // per-wave 32x64 slab (+4 pad)
    int lane = threadIdx.x & 63;
    int wave = threadIdx.x >> 6;
    int r16 = lane & 15, quad = lane >> 4;
    long row0 = (long)blockIdx.x * 128 + wave * 32;   // wave's first row
    long col0 = (long)blockIdx.y * 64;                // block's col tile

    f32x4 acc[2][4] = {};

    // A/B fragment: row = lane&15, k = (lane>>4)*8 + j
    const __hip_bfloat16* ap = zh1 + (row0 + r16) * H + quad * 8;
    const __hip_bfloat16* bp = zh2 + (col0 + r16) * H + quad * 8;
#pragma unroll
    for (int k = 0; k < H; k += 32) {
        bf16x8 a[2], b[4];
#pragma unroll
        for (int mi = 0; mi < 2; ++mi) a[mi] = *(const bf16x8*)(ap + mi * 16 * H + k);
#pragma unroll
        for (int nj = 0; nj < 4; ++nj) b[nj] = *(const bf16x8*)(bp + nj * 16 * H + k);
#pragma unroll
        for (int mi = 0; mi < 2; ++mi)
#pragma unroll
            for (int nj = 0; nj < 4; ++nj)
                acc[mi][nj] = __builtin_amdgcn_mfma_f32_16x16x32_bf16(
                    a[mi], b[nj], acc[mi][nj], 0, 0, 0);
    }

    // e = exp(2*cos) -> wave-private LDS. C/D: col=lane&15, row=quad*4+reg.
    // Bank check: per instr 4 row-chunks of 32B spaced 8 banks -> disjoint.
#pragma unroll
    for (int mi = 0; mi < 2; ++mi) {
#pragma unroll
        for (int nj = 0; nj < 4; ++nj) {
            int lc = nj * 16 + r16;
#pragma unroll
            for (int g = 0; g < 4; ++g)
                elds[wave][mi * 16 + quad * 4 + g][lc] =
                    (_Float16)__expf(acc[mi][nj][g] * 2.0f);
        }
    }

    // Stream this wave's 32x64 pos/neg tile: 16 float4 loads issued, then
    // consumed against the wave's own LDS rows (lgkmcnt-ordered, no barrier).
    const float* pb = pos + row0 * N + col0;
    const float* nb = neg + row0 * N + col0;
    float4 pv[8], nv[8];
#pragma unroll
    for (int it = 0; it < 8; ++it) {
        int idx = lane + it * 64;
        long r = idx >> 4;            // 0..31
        int c = (idx & 15) * 4;       // 0..60
        pv[it] = *(const float4*)(pb + r * N + c);
        nv[it] = *(const float4*)(nb + r * N + c);
    }

    float sp = 0.f, sn = 0.f;
#pragma unroll
    for (int it = 0; it < 8; ++it) {
        int idx = lane + it * 64;
        int r = idx >> 4;
        int c = (idx & 15) * 4;
        h4 e = *(const h4*)&elds[wave][r][c];
        sp = fmaf((float)e.x, pv[it].x, sp);
        sp = fmaf((float)e.y, pv[it].y, sp);
        sp = fmaf((float)e.z, pv[it].z, sp);
        sp = fmaf((float)e.w, pv[it].w, sp);
        sn = fmaf((float)e.x, nv[it].x, sn);
        sn = fmaf((float)e.y, nv[it].y, sn);
        sn = fmaf((float)e.z, nv[it].z, sn);
        sn = fmaf((float)e.w, nv[it].w, sn);
    }

#pragma unroll
    for (int o = 32; o > 0; o >>= 1) {
        sp += __shfl_down(sp, o);
        sn += __shfl_down(sn, o);
    }
    if (lane == 0) {
        int bin = (blockIdx.x * 4 + wave + blockIdx.y * 32) & 255;
        atomicAdd(&bins[bin], sp);
        atomicAdd(&bins[256 + bin], sn);
    }
}

// ---------------------------------------------------------------------------
__global__ void final_kernel(const float* __restrict__ bins, float* __restrict__ out)
{
    int lane = threadIdx.x;  // 64 threads = 1 wave
    float sp = 0.f, sn = 0.f;
#pragma unroll
    for (int k = 0; k < 4; ++k) {
        sp += bins[lane + k * 64];
        sn += bins[256 + lane + k * 64];
    }
#pragma unroll
    for (int o = 32; o > 0; o >>= 1) {
        sp += __shfl_down(sp, o);
        sn += __shfl_down(sn, o);
    }
    if (lane == 0) out[0] = -logf(sp / (sp + sn));
}

// ---------------------------------------------------------------------------
extern "C" void kernel_launch(void* const* d_in, const int* in_sizes, int n_in,
                              void* d_out, int out_size, void* d_ws, size_t ws_size,
                              hipStream_t stream)
{
    const float* v1   = (const float*)d_in[0];
    const float* v2   = (const float*)d_in[1];
    const float* pos  = (const float*)d_in[2];
    const float* neg  = (const float*)d_in[3];
    const float* W    = (const float*)d_in[4];
    const float* bias = (const float*)d_in[5];

    __hip_bfloat16* zh1 = (__hip_bfloat16*)d_ws;                    // 4 MB
    __hip_bfloat16* zh2 = zh1 + (size_t)N * H;                      // 4 MB
    char* p8 = (char*)d_ws + 2ull * N * H * sizeof(__hip_bfloat16);
    __hip_bfloat16* Wb = (__hip_bfloat16*)p8;                       // 128 KB
    float* bins = (float*)(p8 + (size_t)H * H * sizeof(__hip_bfloat16));

    hipMemsetAsync(bins, 0, 512 * sizeof(float), stream);
    convw_kernel<<<64, 256, 0, stream>>>(W, Wb);
    proj_kernel<<<dim3(N / 64, 2), 256, 0, stream>>>(v1, v2, Wb, bias, zh1, zh2);
    contrast_kernel<<<dim3(N / 128, N / 64), 256, 0, stream>>>(zh1, zh2, pos, neg, bins);
    final_kernel<<<1, 64, 0, stream>>>(bins, (float*)d_out);
}

// Round 5
// 645.903 us; speedup vs baseline: 1.1048x; 1.0087x over previous
//
#include <hip/hip_runtime.h>
#include <hip/hip_bf16.h>

#define N 8192
#define H 256

typedef __attribute__((ext_vector_type(8))) short bf16x8;   // 8 bf16 (4 VGPRs)
typedef __attribute__((ext_vector_type(4))) float f32x4;
typedef __attribute__((ext_vector_type(4))) _Float16 h4;

// ---------------------------------------------------------------------------
// Kernel 0: W (fp32, 256x256) -> bf16
__global__ __launch_bounds__(256) void convw_kernel(
    const float* __restrict__ W, __hip_bfloat16* __restrict__ Wb)
{
    int i = (blockIdx.x * 256 + threadIdx.x) * 4;   // 64 blocks cover 65536
    float4 w = *(const float4*)(W + i);
    __hip_bfloat16 o[4] = {__float2bfloat16(w.x), __float2bfloat16(w.y),
                           __float2bfloat16(w.z), __float2bfloat16(w.w)};
    *(short4*)(Wb + i) = *(short4*)o;
}

// ---------------------------------------------------------------------------
// Kernel 1 (MFMA): z = elu(x @ W^T + b); zh = bf16(z/||z||).
// Round-0 harness-verified version, unchanged.
__global__ __launch_bounds__(256) void proj_kernel(
    const float* __restrict__ v1, const float* __restrict__ v2,
    const __hip_bfloat16* __restrict__ Wb, const float* __restrict__ bias,
    __hip_bfloat16* __restrict__ zh1, __hip_bfloat16* __restrict__ zh2)
{
    const float* x = blockIdx.y ? v2 : v1;
    __hip_bfloat16* zh = blockIdx.y ? zh2 : zh1;
    int lane = threadIdx.x & 63, wave = threadIdx.x >> 6;
    int r16 = lane & 15, quad = lane >> 4;

    long arow = (long)blockIdx.x * 64 + wave * 16 + r16;
    const float* xr = x + arow * H + quad * 8;
    const __hip_bfloat16* wb = Wb + r16 * H + quad * 8;

    f32x4 acc[16] = {};
#pragma unroll
    for (int k8 = 0; k8 < 8; ++k8) {
        float4 xa = *(const float4*)(xr + k8 * 32);
        float4 xb = *(const float4*)(xr + k8 * 32 + 4);
        union { bf16x8 v; __hip_bfloat16 h[8]; } u;
        u.h[0] = __float2bfloat16(xa.x); u.h[1] = __float2bfloat16(xa.y);
        u.h[2] = __float2bfloat16(xa.z); u.h[3] = __float2bfloat16(xa.w);
        u.h[4] = __float2bfloat16(xb.x); u.h[5] = __float2bfloat16(xb.y);
        u.h[6] = __float2bfloat16(xb.z); u.h[7] = __float2bfloat16(xb.w);
#pragma unroll
        for (int nt = 0; nt < 16; ++nt) {
            bf16x8 bf = *(const bf16x8*)(wb + nt * 16 * H + k8 * 32);
            acc[nt] = __builtin_amdgcn_mfma_f32_16x16x32_bf16(u.v, bf, acc[nt], 0, 0, 0);
        }
    }

    float ss[4] = {};
#pragma unroll
    for (int nt = 0; nt < 16; ++nt) {
        float bc = bias[nt * 16 + r16];
#pragma unroll
        for (int g = 0; g < 4; ++g) {
            float v = acc[nt][g] + bc;
            v = v > 0.f ? v : (__expf(v) - 1.f);   // ELU alpha=1
            acc[nt][g] = v;
            ss[g] = fmaf(v, v, ss[g]);
        }
    }
    long crow0 = (long)blockIdx.x * 64 + wave * 16 + quad * 4;
#pragma unroll
    for (int g = 0; g < 4; ++g) {
        float s = ss[g];
#pragma unroll
        for (int o = 1; o < 16; o <<= 1) s += __shfl_xor(s, o);
        float inv = rsqrtf(s);
#pragma unroll
        for (int nt = 0; nt < 16; ++nt)
            zh[(crow0 + g) * H + nt * 16 + r16] = __float2bfloat16(acc[nt][g] * inv);
    }
}

// ---------------------------------------------------------------------------
// Kernel 2: fused contrast, barrier-free (round-4 structure) + ASM-PINNED
// stream depth. Block = 128 rows x 64 cols, 4 waves; wave w owns rows
// [w*32, w*32+32) x 64 cols. Phases: MFMA -> exp -> wave-private LDS ->
// 16x global_load_dwordx4 via inline asm (volatile: cannot be sunk) ->
// s_waitcnt vmcnt(0) + sched_barrier(0) -> consume. No __syncthreads.
__global__ __launch_bounds__(256) void contrast_kernel(
    const __hip_bfloat16* __restrict__ zh1, const __hip_bfloat16* __restrict__ zh2,
    const float* __restrict__ pos, const float* __restrict__ neg,
    float* __restrict__ bins)
{
    __shared__ _Float16 elds[4][32][68];   // per-wave 32x64 slab (+4 pad)
    int lane = threadIdx.x & 63;
    int wave = threadIdx.x >> 6;
    int r16 = lane & 15, quad = lane >> 4;
    long row0 = (long)blockIdx.x * 128 + wave * 32;   // wave's first row
    long col0 = (long)blockIdx.y * 64;                // block's col tile

    f32x4 acc[2][4] = {};

    // A/B fragment: row = lane&15, k = (lane>>4)*8 + j
    const __hip_bfloat16* ap = zh1 + (row0 + r16) * H + quad * 8;
    const __hip_bfloat16* bp = zh2 + (col0 + r16) * H + quad * 8;
#pragma unroll
    for (int k = 0; k < H; k += 32) {
        bf16x8 a[2], b[4];
#pragma unroll
        for (int mi = 0; mi < 2; ++mi) a[mi] = *(const bf16x8*)(ap + mi * 16 * H + k);
#pragma unroll
        for (int nj = 0; nj < 4; ++nj) b[nj] = *(const bf16x8*)(bp + nj * 16 * H + k);
#pragma unroll
        for (int mi = 0; mi < 2; ++mi)
#pragma unroll
            for (int nj = 0; nj < 4; ++nj)
                acc[mi][nj] = __builtin_amdgcn_mfma_f32_16x16x32_bf16(
                    a[mi], b[nj], acc[mi][nj], 0, 0, 0);
    }

    // e = exp(2*cos) -> wave-private LDS. C/D: col=lane&15, row=quad*4+reg.
#pragma unroll
    for (int mi = 0; mi < 2; ++mi) {
#pragma unroll
        for (int nj = 0; nj < 4; ++nj) {
            int lc = nj * 16 + r16;
#pragma unroll
            for (int g = 0; g < 4; ++g)
                elds[wave][mi * 16 + quad * 4 + g][lc] =
                    (_Float16)__expf(acc[mi][nj][g] * 2.0f);
        }
    }

    // Stream the wave's 32x64 pos/neg tile. 16 loads asm-pinned in flight
    // (VGPR_Count should read ~100+; if ~60 the pin failed).
    const float* pb = pos + row0 * N + col0;
    const float* nb = neg + row0 * N + col0;
    f32x4 pv[8], nv[8];
#pragma unroll
    for (int it = 0; it < 8; ++it) {
        int idx = lane + it * 64;
        long r = idx >> 4;            // 0..31
        int c = (idx & 15) * 4;       // 0..60
        const float* pa = pb + r * N + c;
        const float* na = nb + r * N + c;
        asm volatile("global_load_dwordx4 %0, %1, off"
                     : "=&v"(pv[it]) : "v"(pa));
        asm volatile("global_load_dwordx4 %0, %1, off"
                     : "=&v"(nv[it]) : "v"(na));
    }
    asm volatile("s_waitcnt vmcnt(0)" ::: "memory");
    __builtin_amdgcn_sched_barrier(0);   // rule #18: nothing crosses the wait

    float sp = 0.f, sn = 0.f;
#pragma unroll
    for (int it = 0; it < 8; ++it) {
        int idx = lane + it * 64;
        int r = idx >> 4;
        int c = (idx & 15) * 4;
        h4 e = *(const h4*)&elds[wave][r][c];
        sp = fmaf((float)e[0], pv[it][0], sp);
        sp = fmaf((float)e[1], pv[it][1], sp);
        sp = fmaf((float)e[2], pv[it][2], sp);
        sp = fmaf((float)e[3], pv[it][3], sp);
        sn = fmaf((float)e[0], nv[it][0], sn);
        sn = fmaf((float)e[1], nv[it][1], sn);
        sn = fmaf((float)e[2], nv[it][2], sn);
        sn = fmaf((float)e[3], nv[it][3], sn);
    }

#pragma unroll
    for (int o = 32; o > 0; o >>= 1) {
        sp += __shfl_down(sp, o);
        sn += __shfl_down(sn, o);
    }
    if (lane == 0) {
        int bin = (blockIdx.x * 4 + wave + blockIdx.y * 32) & 255;
        atomicAdd(&bins[bin], sp);
        atomicAdd(&bins[256 + bin], sn);
    }
}

// ---------------------------------------------------------------------------
__global__ void final_kernel(const float* __restrict__ bins, float* __restrict__ out)
{
    int lane = threadIdx.x;  // 64 threads = 1 wave
    float sp = 0.f, sn = 0.f;
#pragma unroll
    for (int k = 0; k < 4; ++k) {
        sp += bins[lane + k * 64];
        sn += bins[256 + lane + k * 64];
    }
#pragma unroll
    for (int o = 32; o > 0; o >>= 1) {
        sp += __shfl_down(sp, o);
        sn += __shfl_down(sn, o);
    }
    if (lane == 0) out[0] = -logf(sp / (sp + sn));
}

// ---------------------------------------------------------------------------
extern "C" void kernel_launch(void* const* d_in, const int* in_sizes, int n_in,
                              void* d_out, int out_size, void* d_ws, size_t ws_size,
                              hipStream_t stream)
{
    const float* v1   = (const float*)d_in[0];
    const float* v2   = (const float*)d_in[1];
    const float* pos  = (const float*)d_in[2];
    const float* neg  = (const float*)d_in[3];
    const float* W    = (const float*)d_in[4];
    const float* bias = (const float*)d_in[5];

    __hip_bfloat16* zh1 = (__hip_bfloat16*)d_ws;                    // 4 MB
    __hip_bfloat16* zh2 = zh1 + (size_t)N * H;                      // 4 MB
    char* p8 = (char*)d_ws + 2ull * N * H * sizeof(__hip_bfloat16);
    __hip_bfloat16* Wb = (__hip_bfloat16*)p8;                       // 128 KB
    float* bins = (float*)(p8 + (size_t)H * H * sizeof(__hip_bfloat16));

    hipMemsetAsync(bins, 0, 512 * sizeof(float), stream);
    convw_kernel<<<64, 256, 0, stream>>>(W, Wb);
    proj_kernel<<<dim3(N / 64, 2), 256, 0, stream>>>(v1, v2, Wb, bias, zh1, zh2);
    contrast_kernel<<<dim3(N / 128, N / 64), 256, 0, stream>>>(zh1, zh2, pos, neg, bins);
    final_kernel<<<1, 64, 0, stream>>>(bins, (float*)d_out);
}